// Round 3
// baseline (1307.956 us; speedup 1.0000x reference)
//
#include <hip/hip_runtime.h>
#include <hip/hip_bf16.h>
#include <cstdint>
#include <cstddef>

typedef __bf16 bf16;
typedef __attribute__((ext_vector_type(8))) __bf16 bf16x8;
typedef __attribute__((ext_vector_type(4))) float f32x4;

__device__ __forceinline__ void gl_lds16(const bf16* g, bf16* l) {
  __builtin_amdgcn_global_load_lds((const __attribute__((address_space(1))) void*)g,
                                   (__attribute__((address_space(3))) void*)l, 16, 0, 0);
}
__device__ __forceinline__ float bflo(unsigned u) { u <<= 16; return __builtin_bit_cast(float, u); }
__device__ __forceinline__ float bfhi(unsigned u) { u &= 0xffff0000u; return __builtin_bit_cast(float, u); }

// ---------------------------------------------------------------------------
// weight transpose+cast: src (L,K,N) fp32 -> dst (L,N,K) bf16, with explicit
// per-l strides so QKV can be packed into one (2304,768) matrix.
// ---------------------------------------------------------------------------
__global__ __launch_bounds__(256) void wtrans(const float* __restrict__ src,
    bf16* __restrict__ dst, int K, int N, size_t sls, size_t dls) {
  __shared__ float tile[32][33];
  int l = blockIdx.z;
  src += (size_t)l * sls; dst += (size_t)l * dls;
  int n0 = blockIdx.x * 32, k0 = blockIdx.y * 32;
  int tx = threadIdx.x & 31, ty = threadIdx.x >> 5;
#pragma unroll
  for (int i = 0; i < 4; i++) {
    int k = ty + i * 8;
    tile[k][tx] = src[(size_t)(k0 + k) * N + n0 + tx];
  }
  __syncthreads();
#pragma unroll
  for (int i = 0; i < 4; i++) {
    int n = ty + i * 8;
    dst[(size_t)(n0 + n) * K + k0 + tx] = (bf16)tile[tx][n];
  }
}

// ---------------------------------------------------------------------------
// conv1 (3x3, 3->16, VALID) + ReLU + maxpool 2x2 : (16,512,512,3) -> bf16 (16,255,255,16)
// ---------------------------------------------------------------------------
__global__ __launch_bounds__(256) void conv1_pool(const float* __restrict__ x,
    const float* __restrict__ w, const float* __restrict__ bias,
    bf16* __restrict__ out) {
  __shared__ float ws[432];
  __shared__ float bs[16];
  int t = threadIdx.x;
  for (int i = t; i < 432; i += 256) ws[i] = w[i];
  if (t < 16) bs[t] = bias[t];
  __syncthreads();
  int idx = blockIdx.x * 256 + t;
  if (idx >= 16 * 255 * 255) return;
  int xo = idx % 255; int tmp = idx / 255; int yo = tmp % 255; int b = tmp / 255;
  float best[16];
#pragma unroll
  for (int c = 0; c < 16; c++) best[c] = 0.f;
#pragma unroll
  for (int py = 0; py < 2; py++)
#pragma unroll
  for (int px = 0; px < 2; px++) {
    float acc[16];
#pragma unroll
    for (int c = 0; c < 16; c++) acc[c] = bs[c];
    int iy0 = yo * 2 + py, ix0 = xo * 2 + px;
    for (int ky = 0; ky < 3; ky++)
    for (int kx = 0; kx < 3; kx++) {
      const float* xp = x + ((size_t)(b * 512 + iy0 + ky) * 512 + (ix0 + kx)) * 3;
      float v0 = xp[0], v1 = xp[1], v2 = xp[2];
      const float* wp = &ws[((ky * 3 + kx) * 3) * 16];
#pragma unroll
      for (int c = 0; c < 16; c++) acc[c] = fmaf(v0, wp[c], acc[c]);
#pragma unroll
      for (int c = 0; c < 16; c++) acc[c] = fmaf(v1, wp[16 + c], acc[c]);
#pragma unroll
      for (int c = 0; c < 16; c++) acc[c] = fmaf(v2, wp[32 + c], acc[c]);
    }
#pragma unroll
    for (int c = 0; c < 16; c++) best[c] = fmaxf(best[c], acc[c]);
  }
  bf16* op = out + (size_t)idx * 16;
#pragma unroll
  for (int c = 0; c < 16; c++) op[c] = (bf16)best[c];
}

// ---------------------------------------------------------------------------
// conv2 + ReLU + maxpool + pad(1) + patch-extract. LDS halo slot stride 16
// (46 KB total -> 3 blocks/CU); channel reads as ds_read_b64 + shift-unpack.
// ---------------------------------------------------------------------------
#define C2STR 16
__global__ __launch_bounds__(256) void conv2_pool_patch(const bf16* __restrict__ in,
    const float* __restrict__ w, const float* __restrict__ bias,
    bf16* __restrict__ patches) {
  __shared__ bf16 xs[34 * 34 * C2STR];   // 37 KB
  __shared__ float ws[2304];
  __shared__ float bs[16];
  int t = threadIdx.x;
  int tx = blockIdx.x, ty = blockIdx.y, b = blockIdx.z;
  for (int i = t; i < 2304; i += 256) ws[i] = w[i];
  if (t < 16) bs[t] = bias[t];
  int r0 = 32 * ty - 2, c0 = 32 * tx - 2;
  for (int i = t; i < 1156; i += 256) {
    int rr = i / 34, cc = i % 34;
    int gr = min(max(r0 + rr, 0), 254), gc = min(max(c0 + cc, 0), 254);
    const bf16* ip = in + ((size_t)(b * 255 + gr) * 255 + gc) * 16;
    uint4 v0 = *(const uint4*)ip;
    uint4 v1 = *(const uint4*)(ip + 8);
    bf16* op = &xs[i * C2STR];
    *(uint4*)op = v0;
    *(uint4*)(op + 8) = v1;
  }
  __syncthreads();
  int py_ = t >> 4, px_ = t & 15;
  int yp = ty * 16 + py_, xp = tx * 16 + px_;
  bf16* op = patches + ((size_t)(b * 64 + ty * 8 + tx) * 4096 + py_ * 256 + px_ * 16);
  if (yp == 0 || yp == 127 || xp == 0 || xp == 127) {
#pragma unroll
    for (int c = 0; c < 16; c++) op[c] = (bf16)0.f;
    return;
  }
  float best[16];
#pragma unroll
  for (int c = 0; c < 16; c++) best[c] = 0.f;
  for (int py = 0; py < 2; py++)
  for (int px = 0; px < 2; px++) {
    float acc[16];
#pragma unroll
    for (int c = 0; c < 16; c++) acc[c] = bs[c];
    for (int ky = 0; ky < 3; ky++)
    for (int kx = 0; kx < 3; kx++) {
      int lr_ = 2 * py_ + py + ky, lc_ = 2 * px_ + px + kx;
      const uint2* xpp = (const uint2*)&xs[(lr_ * 34 + lc_) * C2STR];
      uint2 w0 = xpp[0], w1 = xpp[1], w2 = xpp[2], w3 = xpp[3];
      float v[16] = {bflo(w0.x), bfhi(w0.x), bflo(w0.y), bfhi(w0.y),
                     bflo(w1.x), bfhi(w1.x), bflo(w1.y), bfhi(w1.y),
                     bflo(w2.x), bfhi(w2.x), bflo(w2.y), bfhi(w2.y),
                     bflo(w3.x), bfhi(w3.x), bflo(w3.y), bfhi(w3.y)};
      const float* wp = &ws[(ky * 3 + kx) * 256];
#pragma unroll
      for (int ci = 0; ci < 16; ci++) {
#pragma unroll
        for (int c = 0; c < 16; c++) acc[c] = fmaf(v[ci], wp[ci * 16 + c], acc[c]);
      }
    }
#pragma unroll
    for (int c = 0; c < 16; c++) best[c] = fmaxf(best[c], acc[c]);
  }
#pragma unroll
  for (int c = 0; c < 16; c++) op[c] = (bf16)best[c];
}

// ---------------------------------------------------------------------------
// 128x128-tile bf16 MFMA GEMM (m97 structure): BK=64, 4 waves (2x2), each wave
// 64x64 = 4x4 of mfma_16x16x32. global_load_lds(16B) staging with XOR chunk
// swizzle (slot = chunk ^ (row&7)) -> conflict-free ds_read_b128 frag loads.
// MODE 0: fp32 partial (z = split-K slice, no bias). MODE 1: bias+relu->bf16.
// ---------------------------------------------------------------------------
template<int MODE>
__global__ __launch_bounds__(256) void gemm128(const bf16* __restrict__ A,
    const bf16* __restrict__ Bt, const float* __restrict__ bias,
    float* __restrict__ Cf, bf16* __restrict__ Cb, int N, int K, int KC) {
  __shared__ bf16 As[8192];
  __shared__ bf16 Bs[8192];
  int s = blockIdx.z;
  int bm = blockIdx.y * 128, bn = blockIdx.x * 128;
  int t = threadIdx.x, lane = t & 63, wave = t >> 6;
  int wm = (wave >> 1) * 64, wn = (wave & 1) * 64;
  int lq = lane >> 4, lr = lane & 15;
  f32x4 acc[4][4];
#pragma unroll
  for (int i = 0; i < 4; i++)
#pragma unroll
  for (int j = 0; j < 4; j++) acc[i][j] = (f32x4){0.f, 0.f, 0.f, 0.f};

  // staging: each wave covers 32 rows (4 instr x 8 rows); lane L -> row L>>3,
  // slot L&7; global chunk fetched = slot ^ (row&7)  (row&7 == L>>3 here).
  int srow = wave * 32 + (lane >> 3);
  int sch = (lane & 7) ^ (lane >> 3);
  const bf16* Ag = A + (size_t)(bm + srow) * K + s * KC + sch * 8;
  const bf16* Bg = Bt + (size_t)(bn + srow) * K + s * KC + sch * 8;
  bf16* AsW = &As[wave * 2048];
  bf16* BsW = &Bs[wave * 2048];

  // frag-read slot offsets (lane-constant): chunk (ks*4+lq) lives at slot ^ (lr&7)
  int key = lr & 7;
  int aoff0 = ((lq ^ key) * 8);
  int aoff1 = (((4 + lq) ^ key) * 8);

  for (int kk = 0; kk < KC; kk += 64) {
    gl_lds16(Ag, AsW);               gl_lds16(Ag + 8 * (size_t)K, AsW + 512);
    gl_lds16(Ag + 16 * (size_t)K, AsW + 1024); gl_lds16(Ag + 24 * (size_t)K, AsW + 1536);
    gl_lds16(Bg, BsW);               gl_lds16(Bg + 8 * (size_t)K, BsW + 512);
    gl_lds16(Bg + 16 * (size_t)K, BsW + 1024); gl_lds16(Bg + 24 * (size_t)K, BsW + 1536);
    Ag += 64; Bg += 64;
    __syncthreads();   // drains vmcnt (global_load_lds) + protects LDS
#pragma unroll
    for (int ks = 0; ks < 2; ks++) {
      int ao = ks ? aoff1 : aoff0;
      bf16x8 af[4], bfr[4];
#pragma unroll
      for (int i = 0; i < 4; i++) af[i] = *(const bf16x8*)&As[(wm + i * 16 + lr) * 64 + ao];
#pragma unroll
      for (int j = 0; j < 4; j++) bfr[j] = *(const bf16x8*)&Bs[(wn + j * 16 + lr) * 64 + ao];
#pragma unroll
      for (int i = 0; i < 4; i++)
#pragma unroll
      for (int j = 0; j < 4; j++)
        acc[i][j] = __builtin_amdgcn_mfma_f32_16x16x32_bf16(af[i], bfr[j], acc[i][j], 0, 0, 0);
    }
    __syncthreads();
  }

  if (MODE == 0) {
    float* Cp = Cf + (size_t)s * 1024 * N;
#pragma unroll
    for (int i = 0; i < 4; i++)
#pragma unroll
    for (int j = 0; j < 4; j++) {
      int col = bn + wn + j * 16 + lr;
      int row0 = bm + wm + i * 16 + lq * 4;      // m89-verified C/D layout
#pragma unroll
      for (int r = 0; r < 4; r++)
        Cp[(size_t)(row0 + r) * N + col] = acc[i][j][r];
    }
  } else {
#pragma unroll
    for (int i = 0; i < 4; i++)
#pragma unroll
    for (int j = 0; j < 4; j++) {
      int col = bn + wn + j * 16 + lr;
      float bb = bias[col];
      int row0 = bm + wm + i * 16 + lq * 4;
#pragma unroll
      for (int r = 0; r < 4; r++) {
        float v = fmaxf(acc[i][j][r] + bb, 0.f);
        Cb[(size_t)(row0 + r) * N + col] = (bf16)v;
      }
    }
  }
}

// ---------------------------------------------------------------------------
// attention: one block per (b,h). QKV = fused split-K partials (2,1024,2304):
// cols [0,768)=q, [768,1536)=k, [1536,2304)=v. Bias added here.
// Output (B,H,S,D)-flat bf16 (reference reshape quirk).
// ---------------------------------------------------------------------------
#define QKVN 2304
#define QKVP 2359296
__global__ __launch_bounds__(256) void attn_kernel(const float* __restrict__ QKV,
    const float* __restrict__ bq, const float* __restrict__ bk, const float* __restrict__ bv,
    bf16* __restrict__ Aout) {
  __shared__ alignas(16) float qs[64 * 68];   // later reused as V^T [d][s]
  __shared__ alignas(16) float ks[64 * 68];
  __shared__ alignas(16) float ss[64 * 68];
  int t = threadIdx.x;
  int bh = blockIdx.x; int b = bh / 12, h = bh % 12;
  size_t rb = (size_t)(b * 64) * QKVN;
  const float* q0 = QKV + rb + h * 64;
  const float* k0 = QKV + rb + 768 + h * 64;
  const float* v0 = QKV + rb + 1536 + h * 64;
  {
    int s = t >> 2, qd = (t & 3) * 16;
#pragma unroll
    for (int j = 0; j < 16; j += 4) {
      float4 qa = *(const float4*)(q0 + (size_t)s * QKVN + qd + j);
      float4 qb2 = *(const float4*)(q0 + QKVP + (size_t)s * QKVN + qd + j);
      float4 qb4 = *(const float4*)(bq + h * 64 + qd + j);
      float4 ka = *(const float4*)(k0 + (size_t)s * QKVN + qd + j);
      float4 kb2 = *(const float4*)(k0 + QKVP + (size_t)s * QKVN + qd + j);
      float4 kb4 = *(const float4*)(bk + h * 64 + qd + j);
      qs[s * 68 + qd + j + 0] = qa.x + qb2.x + qb4.x;
      qs[s * 68 + qd + j + 1] = qa.y + qb2.y + qb4.y;
      qs[s * 68 + qd + j + 2] = qa.z + qb2.z + qb4.z;
      qs[s * 68 + qd + j + 3] = qa.w + qb2.w + qb4.w;
      ks[s * 68 + qd + j + 0] = ka.x + kb2.x + kb4.x;
      ks[s * 68 + qd + j + 1] = ka.y + kb2.y + kb4.y;
      ks[s * 68 + qd + j + 2] = ka.z + kb2.z + kb4.z;
      ks[s * 68 + qd + j + 3] = ka.w + kb2.w + kb4.w;
    }
  }
  __syncthreads();
  int r = t >> 4, c = t & 15;
  {
    float sc[4][4];
#pragma unroll
    for (int i = 0; i < 4; i++)
#pragma unroll
    for (int j = 0; j < 4; j++) sc[i][j] = 0.f;
    for (int k = 0; k < 64; k += 4) {
      float4 qv[4], kv[4];
#pragma unroll
      for (int i = 0; i < 4; i++) qv[i] = *(const float4*)&qs[(r + 16 * i) * 68 + k];
#pragma unroll
      for (int j = 0; j < 4; j++) kv[j] = *(const float4*)&ks[(c + 16 * j) * 68 + k];
#pragma unroll
      for (int i = 0; i < 4; i++)
#pragma unroll
      for (int j = 0; j < 4; j++)
        sc[i][j] += qv[i].x * kv[j].x + qv[i].y * kv[j].y + qv[i].z * kv[j].z + qv[i].w * kv[j].w;
    }
#pragma unroll
    for (int i = 0; i < 4; i++)
#pragma unroll
    for (int j = 0; j < 4; j++)
      ss[(r + 16 * i) * 68 + c + 16 * j] = sc[i][j] * 0.125f;
  }
  __syncthreads();
  {  // V^T into qs with partial-sum + bias
    int d = t & 63, s0 = (t >> 6) * 16;
    float bvd = bv[h * 64 + d];
    alignas(16) float vv[16];
#pragma unroll
    for (int i = 0; i < 16; i++)
      vv[i] = v0[(size_t)(s0 + i) * QKVN + d] + v0[QKVP + (size_t)(s0 + i) * QKVN + d] + bvd;
#pragma unroll
    for (int i = 0; i < 16; i += 4) *(float4*)&qs[d * 68 + s0 + i] = *(float4*)&vv[i];
  }
  {  // softmax
    int lane = t & 63, wave = t >> 6;
    for (int rr = 0; rr < 16; rr++) {
      int row = wave * 16 + rr;
      float v = ss[row * 68 + lane];
      float m = v;
#pragma unroll
      for (int off = 32; off > 0; off >>= 1) m = fmaxf(m, __shfl_xor(m, off));
      float e = __expf(v - m);
      float ssum = e;
#pragma unroll
      for (int off = 32; off > 0; off >>= 1) ssum += __shfl_xor(ssum, off);
      ss[row * 68 + lane] = e / ssum;
    }
  }
  __syncthreads();
  {
    float oc[4][4];
#pragma unroll
    for (int i = 0; i < 4; i++)
#pragma unroll
    for (int j = 0; j < 4; j++) oc[i][j] = 0.f;
    for (int k = 0; k < 64; k += 4) {
      float4 pv[4], vv[4];
#pragma unroll
      for (int i = 0; i < 4; i++) pv[i] = *(const float4*)&ss[(r + 16 * i) * 68 + k];
#pragma unroll
      for (int j = 0; j < 4; j++) vv[j] = *(const float4*)&qs[(c + 16 * j) * 68 + k];
#pragma unroll
      for (int i = 0; i < 4; i++)
#pragma unroll
      for (int j = 0; j < 4; j++)
        oc[i][j] += pv[i].x * vv[j].x + pv[i].y * vv[j].y + pv[i].z * vv[j].z + pv[i].w * vv[j].w;
    }
    bf16* ob = Aout + (size_t)b * 49152 + h * 4096;
#pragma unroll
    for (int i = 0; i < 4; i++)
#pragma unroll
    for (int j = 0; j < 4; j++)
      ob[(r + 16 * i) * 64 + c + 16 * j] = (bf16)oc[i][j];
  }
}

// ---------------------------------------------------------------------------
// residual + S-way split-K partial sum + col bias + LayerNorm; fp32 + bf16 out
// ---------------------------------------------------------------------------
template<int S>
__global__ __launch_bounds__(256) void ln_kernel(const float* __restrict__ X,
    const float* __restrict__ Y, const float* __restrict__ yb,
    const float* __restrict__ g, const float* __restrict__ bta,
    float* __restrict__ Of, bf16* __restrict__ Ob) {
  int row = blockIdx.x, t = threadIdx.x;
  const float* xp = X + (size_t)row * 768;
  float vals[3]; float s = 0.f, s2 = 0.f;
#pragma unroll
  for (int i = 0; i < 3; i++) {
    int e = t + 256 * i;
    float v = xp[e] + yb[e];
#pragma unroll
    for (int p = 0; p < S; p++) v += Y[(size_t)p * 786432 + (size_t)row * 768 + e];
    vals[i] = v; s += v; s2 = fmaf(v, v, s2);
  }
#pragma unroll
  for (int off = 32; off > 0; off >>= 1) { s += __shfl_xor(s, off); s2 += __shfl_xor(s2, off); }
  __shared__ float rs[4], rs2[4];
  if ((t & 63) == 0) { rs[t >> 6] = s; rs2[t >> 6] = s2; }
  __syncthreads();
  s = rs[0] + rs[1] + rs[2] + rs[3];
  s2 = rs2[0] + rs2[1] + rs2[2] + rs2[3];
  float mean = s * (1.f / 768.f);
  float var = s2 * (1.f / 768.f) - mean * mean;
  float rstd = rsqrtf(var + 1e-6f);
  float* ofp = Of + (size_t)row * 768;
  bf16* obp = Ob + (size_t)row * 768;
#pragma unroll
  for (int i = 0; i < 3; i++) {
    int e = t + 256 * i;
    float o = (vals[i] - mean) * rstd * g[e] + bta[e];
    ofp[e] = o; obp[e] = (bf16)o;
  }
}

// S-partial reduce + bias -> fp32 + bf16
template<int S>
__global__ __launch_bounds__(256) void reduceN(const float* __restrict__ P,
    const float* __restrict__ bias, float* __restrict__ Of, bf16* __restrict__ Ob) {
  int row = blockIdx.x, t = threadIdx.x;
#pragma unroll
  for (int i = 0; i < 3; i++) {
    int e = t + 256 * i;
    float v = bias[e];
#pragma unroll
    for (int p = 0; p < S; p++) v += P[(size_t)p * 786432 + (size_t)row * 768 + e];
    Of[(size_t)row * 768 + e] = v;
    Ob[(size_t)row * 768 + e] = (bf16)v;
  }
}

// ---------------------------------------------------------------------------
// mean-pool + head + sigmoid
// ---------------------------------------------------------------------------
__global__ __launch_bounds__(256) void head_kernel(const float* __restrict__ T,
    const float* __restrict__ hw, const float* __restrict__ hbp, float* __restrict__ out) {
  int b = blockIdx.x, t = threadIdx.x;
  float acc = 0.f;
#pragma unroll
  for (int i = 0; i < 3; i++) {
    int e = t + 256 * i;
    float s = 0.f;
    for (int si = 0; si < 64; si++) s += T[(size_t)(b * 64 + si) * 768 + e];
    acc = fmaf(s * (1.f / 64.f), hw[e], acc);
  }
#pragma unroll
  for (int off = 32; off > 0; off >>= 1) acc += __shfl_xor(acc, off);
  __shared__ float rs[4];
  if ((t & 63) == 0) rs[t >> 6] = acc;
  __syncthreads();
  if (t == 0) {
    float z = rs[0] + rs[1] + rs[2] + rs[3] + hbp[0];
    out[b] = 1.f / (1.f + expf(-z));
  }
}

// ---------------------------------------------------------------------------
extern "C" void kernel_launch(void* const* d_in, const int* in_sizes, int n_in,
                              void* d_out, int out_size, void* d_ws, size_t ws_size,
                              hipStream_t stream) {
  const float* x     = (const float*)d_in[0];
  const float* c1w   = (const float*)d_in[1];
  const float* c1b   = (const float*)d_in[2];
  const float* c2w   = (const float*)d_in[3];
  const float* c2b   = (const float*)d_in[4];
  const float* projw = (const float*)d_in[5];
  const float* projb = (const float*)d_in[6];
  const float* Wq    = (const float*)d_in[7];
  const float* bq    = (const float*)d_in[8];
  const float* Wk    = (const float*)d_in[9];
  const float* bk    = (const float*)d_in[10];
  const float* Wv    = (const float*)d_in[11];
  const float* bv    = (const float*)d_in[12];
  const float* Wo    = (const float*)d_in[13];
  const float* bo    = (const float*)d_in[14];
  const float* W1    = (const float*)d_in[15];
  const float* b1    = (const float*)d_in[16];
  const float* W2    = (const float*)d_in[17];
  const float* b2    = (const float*)d_in[18];
  const float* ln1g  = (const float*)d_in[19];
  const float* ln1b  = (const float*)d_in[20];
  const float* ln2g  = (const float*)d_in[21];
  const float* ln2b  = (const float*)d_in[22];
  const float* headw = (const float*)d_in[23];
  const float* headb = (const float*)d_in[24];
  float* out = (float*)d_out;

  char* wp = (char*)d_ws;
  auto alloc = [&](size_t bytes) { char* p = wp; wp += (bytes + 255) & ~(size_t)255; return p; };
  bf16* c1p     = (bf16*)alloc((size_t)16 * 255 * 255 * 16 * 2);   // 33.3 MB
  bf16* patches = (bf16*)alloc((size_t)1024 * 4096 * 2);
  bf16* projT   = (bf16*)alloc((size_t)4096 * 768 * 2);
  bf16* WqkvT   = (bf16*)alloc((size_t)8 * 2304 * 768 * 2);        // fused q|k|v
  bf16* WoT     = (bf16*)alloc((size_t)8 * 768 * 768 * 2);
  bf16* W1T     = (bf16*)alloc((size_t)8 * 768 * 3072 * 2);
  bf16* W2T     = (bf16*)alloc((size_t)8 * 3072 * 768 * 2);
  float* pbuf   = (float*)alloc((size_t)2 * 1024 * 2304 * 4);      // shared split-K partials
  float* tf     = (float*)alloc((size_t)1024 * 768 * 4);
  bf16*  tb     = (bf16*)alloc((size_t)1024 * 768 * 2);
  bf16*  ab     = (bf16*)alloc((size_t)1024 * 768 * 2);
  float* o1f    = (float*)alloc((size_t)1024 * 768 * 4);
  bf16*  o1b    = (bf16*)alloc((size_t)1024 * 768 * 2);
  bf16*  hbuf   = (bf16*)alloc((size_t)1024 * 3072 * 2);

  // weight prep (re-done every call: harness re-poisons ws)
  wtrans<<<dim3(24, 128, 1), 256, 0, stream>>>(projw, projT, 4096, 768, 0, 0);
  wtrans<<<dim3(24, 24, 8), 256, 0, stream>>>(Wq, WqkvT,          768, 768, 589824, 1769472);
  wtrans<<<dim3(24, 24, 8), 256, 0, stream>>>(Wk, WqkvT + 589824, 768, 768, 589824, 1769472);
  wtrans<<<dim3(24, 24, 8), 256, 0, stream>>>(Wv, WqkvT + 1179648, 768, 768, 589824, 1769472);
  wtrans<<<dim3(24, 24, 8), 256, 0, stream>>>(Wo, WoT, 768, 768, 589824, 589824);
  wtrans<<<dim3(96, 24, 8), 256, 0, stream>>>(W1, W1T, 768, 3072, 2359296, 2359296);
  wtrans<<<dim3(24, 96, 8), 256, 0, stream>>>(W2, W2T, 3072, 768, 2359296, 2359296);

  conv1_pool<<<4065, 256, 0, stream>>>(x, c1w, c1b, c1p);
  conv2_pool_patch<<<dim3(8, 8, 16), 256, 0, stream>>>(c1p, c2w, c2b, patches);
  gemm128<0><<<dim3(6, 8, 4), 256, 0, stream>>>(patches, projT, nullptr, pbuf, nullptr, 768, 4096, 1024);
  reduceN<4><<<1024, 256, 0, stream>>>(pbuf, projb, tf, tb);

  for (int i = 0; i < 8; i++) {
    gemm128<0><<<dim3(18, 8, 2), 256, 0, stream>>>(tb, WqkvT + (size_t)i * 1769472,
        nullptr, pbuf, nullptr, 2304, 768, 384);
    attn_kernel<<<192, 256, 0, stream>>>(pbuf, bq + i * 768, bk + i * 768, bv + i * 768, ab);
    gemm128<0><<<dim3(6, 8, 4), 256, 0, stream>>>(ab, WoT + (size_t)i * 589824,
        nullptr, pbuf, nullptr, 768, 768, 192);
    ln_kernel<4><<<1024, 256, 0, stream>>>(tf, pbuf, bo + i * 768,
        ln1g + i * 768, ln1b + i * 768, o1f, o1b);
    gemm128<1><<<dim3(24, 8, 1), 256, 0, stream>>>(o1b, W1T + (size_t)i * 2359296,
        b1 + i * 3072, nullptr, hbuf, 3072, 768, 768);
    gemm128<0><<<dim3(6, 8, 4), 256, 0, stream>>>(hbuf, W2T + (size_t)i * 2359296,
        nullptr, pbuf, nullptr, 768, 3072, 768);
    ln_kernel<4><<<1024, 256, 0, stream>>>(o1f, pbuf, b2 + i * 768,
        ln2g + i * 768, ln2b + i * 768, tf, tb);
  }
  head_kernel<<<16, 256, 0, stream>>>(tf, headw, headb, out);
}

// Round 4
// 1198.231 us; speedup vs baseline: 1.0916x; 1.0916x over previous
//
#include <hip/hip_runtime.h>
#include <hip/hip_bf16.h>
#include <cstdint>
#include <cstddef>

typedef __bf16 bf16;
typedef __attribute__((ext_vector_type(8))) __bf16 bf16x8;
typedef __attribute__((ext_vector_type(4))) float f32x4;

__device__ __forceinline__ void gl_lds16(const bf16* g, bf16* l) {
  __builtin_amdgcn_global_load_lds((const __attribute__((address_space(1))) void*)g,
                                   (__attribute__((address_space(3))) void*)l, 16, 0, 0);
}
__device__ __forceinline__ float bflo(unsigned u) { u <<= 16; return __builtin_bit_cast(float, u); }
__device__ __forceinline__ float bfhi(unsigned u) { u &= 0xffff0000u; return __builtin_bit_cast(float, u); }

// ---------------------------------------------------------------------------
// weight transpose+cast: src (L,K,N) fp32 -> dst (L,N,K) bf16
// ---------------------------------------------------------------------------
__global__ __launch_bounds__(256) void wtrans(const float* __restrict__ src,
    bf16* __restrict__ dst, int K, int N, size_t sls, size_t dls) {
  __shared__ float tile[32][33];
  int l = blockIdx.z;
  src += (size_t)l * sls; dst += (size_t)l * dls;
  int n0 = blockIdx.x * 32, k0 = blockIdx.y * 32;
  int tx = threadIdx.x & 31, ty = threadIdx.x >> 5;
#pragma unroll
  for (int i = 0; i < 4; i++) {
    int k = ty + i * 8;
    tile[k][tx] = src[(size_t)(k0 + k) * N + n0 + tx];
  }
  __syncthreads();
#pragma unroll
  for (int i = 0; i < 4; i++) {
    int n = ty + i * 8;
    dst[(size_t)(n0 + n) * K + k0 + tx] = (bf16)tile[tx][n];
  }
}

// ---------------------------------------------------------------------------
// conv1 (3x3, 3->16, VALID) + ReLU + maxpool 2x2 : (16,512,512,3) -> bf16 (16,255,255,16)
// ---------------------------------------------------------------------------
__global__ __launch_bounds__(256) void conv1_pool(const float* __restrict__ x,
    const float* __restrict__ w, const float* __restrict__ bias,
    bf16* __restrict__ out) {
  __shared__ float ws[432];
  __shared__ float bs[16];
  int t = threadIdx.x;
  for (int i = t; i < 432; i += 256) ws[i] = w[i];
  if (t < 16) bs[t] = bias[t];
  __syncthreads();
  int idx = blockIdx.x * 256 + t;
  if (idx >= 16 * 255 * 255) return;
  int xo = idx % 255; int tmp = idx / 255; int yo = tmp % 255; int b = tmp / 255;
  float best[16];
#pragma unroll
  for (int c = 0; c < 16; c++) best[c] = 0.f;
#pragma unroll
  for (int py = 0; py < 2; py++)
#pragma unroll
  for (int px = 0; px < 2; px++) {
    float acc[16];
#pragma unroll
    for (int c = 0; c < 16; c++) acc[c] = bs[c];
    int iy0 = yo * 2 + py, ix0 = xo * 2 + px;
    for (int ky = 0; ky < 3; ky++)
    for (int kx = 0; kx < 3; kx++) {
      const float* xp = x + ((size_t)(b * 512 + iy0 + ky) * 512 + (ix0 + kx)) * 3;
      float v0 = xp[0], v1 = xp[1], v2 = xp[2];
      const float* wp = &ws[((ky * 3 + kx) * 3) * 16];
#pragma unroll
      for (int c = 0; c < 16; c++) acc[c] = fmaf(v0, wp[c], acc[c]);
#pragma unroll
      for (int c = 0; c < 16; c++) acc[c] = fmaf(v1, wp[16 + c], acc[c]);
#pragma unroll
      for (int c = 0; c < 16; c++) acc[c] = fmaf(v2, wp[32 + c], acc[c]);
    }
#pragma unroll
    for (int c = 0; c < 16; c++) best[c] = fmaxf(best[c], acc[c]);
  }
  bf16* op = out + (size_t)idx * 16;
#pragma unroll
  for (int c = 0; c < 16; c++) op[c] = (bf16)best[c];
}

// ---------------------------------------------------------------------------
// conv2 + ReLU + maxpool + pad(1) + patch-extract (LDS halo, slot stride 16)
// ---------------------------------------------------------------------------
#define C2STR 16
__global__ __launch_bounds__(256) void conv2_pool_patch(const bf16* __restrict__ in,
    const float* __restrict__ w, const float* __restrict__ bias,
    bf16* __restrict__ patches) {
  __shared__ bf16 xs[34 * 34 * C2STR];
  __shared__ float ws[2304];
  __shared__ float bs[16];
  int t = threadIdx.x;
  int tx = blockIdx.x, ty = blockIdx.y, b = blockIdx.z;
  for (int i = t; i < 2304; i += 256) ws[i] = w[i];
  if (t < 16) bs[t] = bias[t];
  int r0 = 32 * ty - 2, c0 = 32 * tx - 2;
  for (int i = t; i < 1156; i += 256) {
    int rr = i / 34, cc = i % 34;
    int gr = min(max(r0 + rr, 0), 254), gc = min(max(c0 + cc, 0), 254);
    const bf16* ip = in + ((size_t)(b * 255 + gr) * 255 + gc) * 16;
    uint4 v0 = *(const uint4*)ip;
    uint4 v1 = *(const uint4*)(ip + 8);
    bf16* op = &xs[i * C2STR];
    *(uint4*)op = v0;
    *(uint4*)(op + 8) = v1;
  }
  __syncthreads();
  int py_ = t >> 4, px_ = t & 15;
  int yp = ty * 16 + py_, xp = tx * 16 + px_;
  bf16* op = patches + ((size_t)(b * 64 + ty * 8 + tx) * 4096 + py_ * 256 + px_ * 16);
  if (yp == 0 || yp == 127 || xp == 0 || xp == 127) {
#pragma unroll
    for (int c = 0; c < 16; c++) op[c] = (bf16)0.f;
    return;
  }
  float best[16];
#pragma unroll
  for (int c = 0; c < 16; c++) best[c] = 0.f;
  for (int py = 0; py < 2; py++)
  for (int px = 0; px < 2; px++) {
    float acc[16];
#pragma unroll
    for (int c = 0; c < 16; c++) acc[c] = bs[c];
    for (int ky = 0; ky < 3; ky++)
    for (int kx = 0; kx < 3; kx++) {
      int lr_ = 2 * py_ + py + ky, lc_ = 2 * px_ + px + kx;
      const uint2* xpp = (const uint2*)&xs[(lr_ * 34 + lc_) * C2STR];
      uint2 w0 = xpp[0], w1 = xpp[1], w2 = xpp[2], w3 = xpp[3];
      float v[16] = {bflo(w0.x), bfhi(w0.x), bflo(w0.y), bfhi(w0.y),
                     bflo(w1.x), bfhi(w1.x), bflo(w1.y), bfhi(w1.y),
                     bflo(w2.x), bfhi(w2.x), bflo(w2.y), bfhi(w2.y),
                     bflo(w3.x), bfhi(w3.x), bflo(w3.y), bfhi(w3.y)};
      const float* wp = &ws[(ky * 3 + kx) * 256];
#pragma unroll
      for (int ci = 0; ci < 16; ci++) {
#pragma unroll
        for (int c = 0; c < 16; c++) acc[c] = fmaf(v[ci], wp[ci * 16 + c], acc[c]);
      }
    }
#pragma unroll
    for (int c = 0; c < 16; c++) best[c] = fmaxf(best[c], acc[c]);
  }
#pragma unroll
  for (int c = 0; c < 16; c++) op[c] = (bf16)best[c];
}

// ---------------------------------------------------------------------------
// 64x64-tile bf16 MFMA GEMM: BK=64, 4 waves (2x2), wave tile 32x32 (2x2 of
// 16x16x32). global_load_lds(16B) staging, LDS layout == global (row-major
// K-chunks, no pad) -> lane-contiguous DMA + m97-pattern ds_read_b128 frags.
// MODE 0: fp32 partial (blockIdx.z = split slice). MODE 1: bias+relu -> bf16.
// ---------------------------------------------------------------------------
template<int MODE>
__global__ __launch_bounds__(256) void gemm64(const bf16* __restrict__ A,
    const bf16* __restrict__ Bt, const float* __restrict__ bias,
    float* __restrict__ Cf, bf16* __restrict__ Cb, int N, int K, int KC) {
  __shared__ bf16 As[4096];
  __shared__ bf16 Bs[4096];
  int s = blockIdx.z;
  int bm = blockIdx.y * 64, bn = blockIdx.x * 64;
  int t = threadIdx.x, lane = t & 63, wave = t >> 6;
  int wm = (wave >> 1) * 32, wn = (wave & 1) * 32;
  int lq = lane >> 4, lr = lane & 15;
  f32x4 acc[2][2];
#pragma unroll
  for (int i = 0; i < 2; i++)
#pragma unroll
  for (int j = 0; j < 2; j++) acc[i][j] = (f32x4){0.f, 0.f, 0.f, 0.f};

  // staging: instr i covers rows [i*32 + wave*8, +8); lane -> row lane>>3, chunk lane&7
  int srow = wave * 8 + (lane >> 3);
  int sch = lane & 7;
  const bf16* Ag = A + (size_t)(bm + srow) * K + s * KC + sch * 8;
  const bf16* Bg = Bt + (size_t)(bn + srow) * K + s * KC + sch * 8;
  bf16* AsW = &As[wave * 512];
  bf16* BsW = &Bs[wave * 512];

  for (int kk = 0; kk < KC; kk += 64) {
    gl_lds16(Ag, AsW);
    gl_lds16(Ag + 32 * (size_t)K, AsW + 2048);
    gl_lds16(Bg, BsW);
    gl_lds16(Bg + 32 * (size_t)K, BsW + 2048);
    Ag += 64; Bg += 64;
    __syncthreads();   // drains vmcnt (global_load_lds) + protects LDS
#pragma unroll
    for (int ks = 0; ks < 2; ks++) {
      int ao = ks * 32 + lq * 8;
      bf16x8 af0 = *(const bf16x8*)&As[(wm + lr) * 64 + ao];
      bf16x8 af1 = *(const bf16x8*)&As[(wm + 16 + lr) * 64 + ao];
      bf16x8 bf0 = *(const bf16x8*)&Bs[(wn + lr) * 64 + ao];
      bf16x8 bf1 = *(const bf16x8*)&Bs[(wn + 16 + lr) * 64 + ao];
      acc[0][0] = __builtin_amdgcn_mfma_f32_16x16x32_bf16(af0, bf0, acc[0][0], 0, 0, 0);
      acc[0][1] = __builtin_amdgcn_mfma_f32_16x16x32_bf16(af0, bf1, acc[0][1], 0, 0, 0);
      acc[1][0] = __builtin_amdgcn_mfma_f32_16x16x32_bf16(af1, bf0, acc[1][0], 0, 0, 0);
      acc[1][1] = __builtin_amdgcn_mfma_f32_16x16x32_bf16(af1, bf1, acc[1][1], 0, 0, 0);
    }
    __syncthreads();
  }

  if (MODE == 0) {
    float* Cp = Cf + (size_t)s * 1024 * N;
#pragma unroll
    for (int i = 0; i < 2; i++)
#pragma unroll
    for (int j = 0; j < 2; j++) {
      int col = bn + wn + j * 16 + lr;
      int row0 = bm + wm + i * 16 + lq * 4;      // m89-verified C/D layout
#pragma unroll
      for (int r = 0; r < 4; r++)
        Cp[(size_t)(row0 + r) * N + col] = acc[i][j][r];
    }
  } else {
#pragma unroll
    for (int i = 0; i < 2; i++)
#pragma unroll
    for (int j = 0; j < 2; j++) {
      int col = bn + wn + j * 16 + lr;
      float bb = bias[col];
      int row0 = bm + wm + i * 16 + lq * 4;
#pragma unroll
      for (int r = 0; r < 4; r++) {
        float v = fmaxf(acc[i][j][r] + bb, 0.f);
        Cb[(size_t)(row0 + r) * N + col] = (bf16)v;
      }
    }
  }
}

// ---------------------------------------------------------------------------
// attention: one block per (b,h). QKV = fused split-K partials (2,1024,2304):
// cols [0,768)=q, [768,1536)=k, [1536,2304)=v. Bias added here.
// Output (B,H,S,D)-flat bf16 (reference reshape quirk).
// ---------------------------------------------------------------------------
#define QKVN 2304
#define QKVP 2359296
__global__ __launch_bounds__(256) void attn_kernel(const float* __restrict__ QKV,
    const float* __restrict__ bq, const float* __restrict__ bk, const float* __restrict__ bv,
    bf16* __restrict__ Aout) {
  __shared__ alignas(16) float qs[64 * 68];   // later reused as V^T [d][s]
  __shared__ alignas(16) float ks[64 * 68];
  __shared__ alignas(16) float ss[64 * 68];
  int t = threadIdx.x;
  int bh = blockIdx.x; int b = bh / 12, h = bh % 12;
  size_t rb = (size_t)(b * 64) * QKVN;
  const float* q0 = QKV + rb + h * 64;
  const float* k0 = QKV + rb + 768 + h * 64;
  const float* v0 = QKV + rb + 1536 + h * 64;
  {
    int s = t >> 2, qd = (t & 3) * 16;
#pragma unroll
    for (int j = 0; j < 16; j += 4) {
      float4 qa = *(const float4*)(q0 + (size_t)s * QKVN + qd + j);
      float4 qb2 = *(const float4*)(q0 + QKVP + (size_t)s * QKVN + qd + j);
      float4 qb4 = *(const float4*)(bq + h * 64 + qd + j);
      float4 ka = *(const float4*)(k0 + (size_t)s * QKVN + qd + j);
      float4 kb2 = *(const float4*)(k0 + QKVP + (size_t)s * QKVN + qd + j);
      float4 kb4 = *(const float4*)(bk + h * 64 + qd + j);
      qs[s * 68 + qd + j + 0] = qa.x + qb2.x + qb4.x;
      qs[s * 68 + qd + j + 1] = qa.y + qb2.y + qb4.y;
      qs[s * 68 + qd + j + 2] = qa.z + qb2.z + qb4.z;
      qs[s * 68 + qd + j + 3] = qa.w + qb2.w + qb4.w;
      ks[s * 68 + qd + j + 0] = ka.x + kb2.x + kb4.x;
      ks[s * 68 + qd + j + 1] = ka.y + kb2.y + kb4.y;
      ks[s * 68 + qd + j + 2] = ka.z + kb2.z + kb4.z;
      ks[s * 68 + qd + j + 3] = ka.w + kb2.w + kb4.w;
    }
  }
  __syncthreads();
  int r = t >> 4, c = t & 15;
  {
    float sc[4][4];
#pragma unroll
    for (int i = 0; i < 4; i++)
#pragma unroll
    for (int j = 0; j < 4; j++) sc[i][j] = 0.f;
    for (int k = 0; k < 64; k += 4) {
      float4 qv[4], kv[4];
#pragma unroll
      for (int i = 0; i < 4; i++) qv[i] = *(const float4*)&qs[(r + 16 * i) * 68 + k];
#pragma unroll
      for (int j = 0; j < 4; j++) kv[j] = *(const float4*)&ks[(c + 16 * j) * 68 + k];
#pragma unroll
      for (int i = 0; i < 4; i++)
#pragma unroll
      for (int j = 0; j < 4; j++)
        sc[i][j] += qv[i].x * kv[j].x + qv[i].y * kv[j].y + qv[i].z * kv[j].z + qv[i].w * kv[j].w;
    }
#pragma unroll
    for (int i = 0; i < 4; i++)
#pragma unroll
    for (int j = 0; j < 4; j++)
      ss[(r + 16 * i) * 68 + c + 16 * j] = sc[i][j] * 0.125f;
  }
  __syncthreads();
  {  // V^T into qs with partial-sum + bias
    int d = t & 63, s0 = (t >> 6) * 16;
    float bvd = bv[h * 64 + d];
    alignas(16) float vv[16];
#pragma unroll
    for (int i = 0; i < 16; i++)
      vv[i] = v0[(size_t)(s0 + i) * QKVN + d] + v0[QKVP + (size_t)(s0 + i) * QKVN + d] + bvd;
#pragma unroll
    for (int i = 0; i < 16; i += 4) *(float4*)&qs[d * 68 + s0 + i] = *(float4*)&vv[i];
  }
  {  // softmax
    int lane = t & 63, wave = t >> 6;
    for (int rr = 0; rr < 16; rr++) {
      int row = wave * 16 + rr;
      float v = ss[row * 68 + lane];
      float m = v;
#pragma unroll
      for (int off = 32; off > 0; off >>= 1) m = fmaxf(m, __shfl_xor(m, off));
      float e = __expf(v - m);
      float ssum = e;
#pragma unroll
      for (int off = 32; off > 0; off >>= 1) ssum += __shfl_xor(ssum, off);
      ss[row * 68 + lane] = e / ssum;
    }
  }
  __syncthreads();
  {
    float oc[4][4];
#pragma unroll
    for (int i = 0; i < 4; i++)
#pragma unroll
    for (int j = 0; j < 4; j++) oc[i][j] = 0.f;
    for (int k = 0; k < 64; k += 4) {
      float4 pv[4], vv[4];
#pragma unroll
      for (int i = 0; i < 4; i++) pv[i] = *(const float4*)&ss[(r + 16 * i) * 68 + k];
#pragma unroll
      for (int j = 0; j < 4; j++) vv[j] = *(const float4*)&qs[(c + 16 * j) * 68 + k];
#pragma unroll
      for (int i = 0; i < 4; i++)
#pragma unroll
      for (int j = 0; j < 4; j++)
        oc[i][j] += pv[i].x * vv[j].x + pv[i].y * vv[j].y + pv[i].z * vv[j].z + pv[i].w * vv[j].w;
    }
    bf16* ob = Aout + (size_t)b * 49152 + h * 4096;
#pragma unroll
    for (int i = 0; i < 4; i++)
#pragma unroll
    for (int j = 0; j < 4; j++)
      ob[(r + 16 * i) * 64 + c + 16 * j] = (bf16)oc[i][j];
  }
}

// ---------------------------------------------------------------------------
// residual + S-way split-K partial sum + col bias + LayerNorm; fp32 + bf16 out
// ---------------------------------------------------------------------------
template<int S>
__global__ __launch_bounds__(256) void ln_kernel(const float* __restrict__ X,
    const float* __restrict__ Y, const float* __restrict__ yb,
    const float* __restrict__ g, const float* __restrict__ bta,
    float* __restrict__ Of, bf16* __restrict__ Ob) {
  int row = blockIdx.x, t = threadIdx.x;
  const float* xp = X + (size_t)row * 768;
  float vals[3]; float s = 0.f, s2 = 0.f;
#pragma unroll
  for (int i = 0; i < 3; i++) {
    int e = t + 256 * i;
    float v = xp[e] + yb[e];
#pragma unroll
    for (int p = 0; p < S; p++) v += Y[(size_t)p * 786432 + (size_t)row * 768 + e];
    vals[i] = v; s += v; s2 = fmaf(v, v, s2);
  }
#pragma unroll
  for (int off = 32; off > 0; off >>= 1) { s += __shfl_xor(s, off); s2 += __shfl_xor(s2, off); }
  __shared__ float rs[4], rs2[4];
  if ((t & 63) == 0) { rs[t >> 6] = s; rs2[t >> 6] = s2; }
  __syncthreads();
  s = rs[0] + rs[1] + rs[2] + rs[3];
  s2 = rs2[0] + rs2[1] + rs2[2] + rs2[3];
  float mean = s * (1.f / 768.f);
  float var = s2 * (1.f / 768.f) - mean * mean;
  float rstd = rsqrtf(var + 1e-6f);
  float* ofp = Of + (size_t)row * 768;
  bf16* obp = Ob + (size_t)row * 768;
#pragma unroll
  for (int i = 0; i < 3; i++) {
    int e = t + 256 * i;
    float o = (vals[i] - mean) * rstd * g[e] + bta[e];
    ofp[e] = o; obp[e] = (bf16)o;
  }
}

// S-partial reduce + bias -> fp32 + bf16
template<int S>
__global__ __launch_bounds__(256) void reduceN(const float* __restrict__ P,
    const float* __restrict__ bias, float* __restrict__ Of, bf16* __restrict__ Ob) {
  int row = blockIdx.x, t = threadIdx.x;
#pragma unroll
  for (int i = 0; i < 3; i++) {
    int e = t + 256 * i;
    float v = bias[e];
#pragma unroll
    for (int p = 0; p < S; p++) v += P[(size_t)p * 786432 + (size_t)row * 768 + e];
    Of[(size_t)row * 768 + e] = v;
    Ob[(size_t)row * 768 + e] = (bf16)v;
  }
}

// ---------------------------------------------------------------------------
// mean-pool + head + sigmoid
// ---------------------------------------------------------------------------
__global__ __launch_bounds__(256) void head_kernel(const float* __restrict__ T,
    const float* __restrict__ hw, const float* __restrict__ hbp, float* __restrict__ out) {
  int b = blockIdx.x, t = threadIdx.x;
  float acc = 0.f;
#pragma unroll
  for (int i = 0; i < 3; i++) {
    int e = t + 256 * i;
    float s = 0.f;
    for (int si = 0; si < 64; si++) s += T[(size_t)(b * 64 + si) * 768 + e];
    acc = fmaf(s * (1.f / 64.f), hw[e], acc);
  }
#pragma unroll
  for (int off = 32; off > 0; off >>= 1) acc += __shfl_xor(acc, off);
  __shared__ float rs[4];
  if ((t & 63) == 0) rs[t >> 6] = acc;
  __syncthreads();
  if (t == 0) {
    float z = rs[0] + rs[1] + rs[2] + rs[3] + hbp[0];
    out[b] = 1.f / (1.f + expf(-z));
  }
}

// ---------------------------------------------------------------------------
extern "C" void kernel_launch(void* const* d_in, const int* in_sizes, int n_in,
                              void* d_out, int out_size, void* d_ws, size_t ws_size,
                              hipStream_t stream) {
  const float* x     = (const float*)d_in[0];
  const float* c1w   = (const float*)d_in[1];
  const float* c1b   = (const float*)d_in[2];
  const float* c2w   = (const float*)d_in[3];
  const float* c2b   = (const float*)d_in[4];
  const float* projw = (const float*)d_in[5];
  const float* projb = (const float*)d_in[6];
  const float* Wq    = (const float*)d_in[7];
  const float* bq    = (const float*)d_in[8];
  const float* Wk    = (const float*)d_in[9];
  const float* bk    = (const float*)d_in[10];
  const float* Wv    = (const float*)d_in[11];
  const float* bv    = (const float*)d_in[12];
  const float* Wo    = (const float*)d_in[13];
  const float* bo    = (const float*)d_in[14];
  const float* W1    = (const float*)d_in[15];
  const float* b1    = (const float*)d_in[16];
  const float* W2    = (const float*)d_in[17];
  const float* b2    = (const float*)d_in[18];
  const float* ln1g  = (const float*)d_in[19];
  const float* ln1b  = (const float*)d_in[20];
  const float* ln2g  = (const float*)d_in[21];
  const float* ln2b  = (const float*)d_in[22];
  const float* headw = (const float*)d_in[23];
  const float* headb = (const float*)d_in[24];
  float* out = (float*)d_out;

  char* wp = (char*)d_ws;
  auto alloc = [&](size_t bytes) { char* p = wp; wp += (bytes + 255) & ~(size_t)255; return p; };
  bf16* c1p     = (bf16*)alloc((size_t)16 * 255 * 255 * 16 * 2);   // 33.3 MB
  bf16* patches = (bf16*)alloc((size_t)1024 * 4096 * 2);
  bf16* projT   = (bf16*)alloc((size_t)4096 * 768 * 2);
  bf16* WqkvT   = (bf16*)alloc((size_t)8 * 2304 * 768 * 2);        // fused q|k|v
  bf16* WoT     = (bf16*)alloc((size_t)8 * 768 * 768 * 2);
  bf16* W1T     = (bf16*)alloc((size_t)8 * 768 * 3072 * 2);
  bf16* W2T     = (bf16*)alloc((size_t)8 * 3072 * 768 * 2);
  float* pbuf   = (float*)alloc((size_t)2 * 1024 * 2304 * 4);      // shared split-K partials
  float* tf     = (float*)alloc((size_t)1024 * 768 * 4);
  bf16*  tb     = (bf16*)alloc((size_t)1024 * 768 * 2);
  bf16*  ab     = (bf16*)alloc((size_t)1024 * 768 * 2);
  float* o1f    = (float*)alloc((size_t)1024 * 768 * 4);
  bf16*  o1b    = (bf16*)alloc((size_t)1024 * 768 * 2);
  bf16*  hbuf   = (bf16*)alloc((size_t)1024 * 3072 * 2);

  // weight prep (re-done every call: harness re-poisons ws)
  wtrans<<<dim3(24, 128, 1), 256, 0, stream>>>(projw, projT, 4096, 768, 0, 0);
  wtrans<<<dim3(24, 24, 8), 256, 0, stream>>>(Wq, WqkvT,           768, 768, 589824, 1769472);
  wtrans<<<dim3(24, 24, 8), 256, 0, stream>>>(Wk, WqkvT + 589824,  768, 768, 589824, 1769472);
  wtrans<<<dim3(24, 24, 8), 256, 0, stream>>>(Wv, WqkvT + 1179648, 768, 768, 589824, 1769472);
  wtrans<<<dim3(24, 24, 8), 256, 0, stream>>>(Wo, WoT, 768, 768, 589824, 589824);
  wtrans<<<dim3(96, 24, 8), 256, 0, stream>>>(W1, W1T, 768, 3072, 2359296, 2359296);
  wtrans<<<dim3(24, 96, 8), 256, 0, stream>>>(W2, W2T, 3072, 768, 2359296, 2359296);

  conv1_pool<<<4065, 256, 0, stream>>>(x, c1w, c1b, c1p);
  conv2_pool_patch<<<dim3(8, 8, 16), 256, 0, stream>>>(c1p, c2w, c2b, patches);
  gemm64<0><<<dim3(12, 16, 4), 256, 0, stream>>>(patches, projT, nullptr, pbuf, nullptr, 768, 4096, 1024);
  reduceN<4><<<1024, 256, 0, stream>>>(pbuf, projb, tf, tb);

  for (int i = 0; i < 8; i++) {
    gemm64<0><<<dim3(36, 16, 2), 256, 0, stream>>>(tb, WqkvT + (size_t)i * 1769472,
        nullptr, pbuf, nullptr, 2304, 768, 384);
    attn_kernel<<<192, 256, 0, stream>>>(pbuf, bq + i * 768, bk + i * 768, bv + i * 768, ab);
    gemm64<0><<<dim3(12, 16, 2), 256, 0, stream>>>(ab, WoT + (size_t)i * 589824,
        nullptr, pbuf, nullptr, 768, 768, 384);
    ln_kernel<2><<<1024, 256, 0, stream>>>(tf, pbuf, bo + i * 768,
        ln1g + i * 768, ln1b + i * 768, o1f, o1b);
    gemm64<1><<<dim3(48, 16, 1), 256, 0, stream>>>(o1b, W1T + (size_t)i * 2359296,
        b1 + i * 3072, nullptr, hbuf, 3072, 768, 768);
    gemm64<0><<<dim3(12, 16, 4), 256, 0, stream>>>(hbuf, W2T + (size_t)i * 2359296,
        nullptr, pbuf, nullptr, 768, 3072, 768);
    ln_kernel<4><<<1024, 256, 0, stream>>>(o1f, pbuf, b2 + i * 768,
        ln2g + i * 768, ln2b + i * 768, tf, tb);
  }
  head_kernel<<<16, 256, 0, stream>>>(tf, headw, headb, out);
}

// Round 5
// 1138.793 us; speedup vs baseline: 1.1485x; 1.0522x over previous
//
#include <hip/hip_runtime.h>
#include <hip/hip_bf16.h>
#include <cstdint>
#include <cstddef>

typedef __bf16 bf16;
typedef __attribute__((ext_vector_type(8))) __bf16 bf16x8;
typedef __attribute__((ext_vector_type(4))) float f32x4;

__device__ __forceinline__ void gl_lds16(const bf16* g, bf16* l) {
  __builtin_amdgcn_global_load_lds((const __attribute__((address_space(1))) void*)g,
                                   (__attribute__((address_space(3))) void*)l, 16, 0, 0);
}
__device__ __forceinline__ float bflo(unsigned u) { u <<= 16; return __builtin_bit_cast(float, u); }
__device__ __forceinline__ float bfhi(unsigned u) { u &= 0xffff0000u; return __builtin_bit_cast(float, u); }

// ---------------------------------------------------------------------------
// weight transpose+cast: src (L,K,N) fp32 -> dst (L,N,K) bf16
// ---------------------------------------------------------------------------
__global__ __launch_bounds__(256) void wtrans(const float* __restrict__ src,
    bf16* __restrict__ dst, int K, int N, size_t sls, size_t dls) {
  __shared__ float tile[32][33];
  int l = blockIdx.z;
  src += (size_t)l * sls; dst += (size_t)l * dls;
  int n0 = blockIdx.x * 32, k0 = blockIdx.y * 32;
  int tx = threadIdx.x & 31, ty = threadIdx.x >> 5;
#pragma unroll
  for (int i = 0; i < 4; i++) {
    int k = ty + i * 8;
    tile[k][tx] = src[(size_t)(k0 + k) * N + n0 + tx];
  }
  __syncthreads();
#pragma unroll
  for (int i = 0; i < 4; i++) {
    int n = ty + i * 8;
    dst[(size_t)(n0 + n) * K + k0 + tx] = (bf16)tile[tx][n];
  }
}

// ---------------------------------------------------------------------------
// conv1 (3x3, 3->16, VALID) + ReLU + maxpool 2x2 : (16,512,512,3) -> bf16
// (16,255,255,16). Weights read with uniform (scalar) loads; pool unrolled.
// ---------------------------------------------------------------------------
__global__ __launch_bounds__(256) void conv1_pool(const float* __restrict__ x,
    const float* __restrict__ w, const float* __restrict__ bias,
    bf16* __restrict__ out) {
  int idx = blockIdx.x * 256 + threadIdx.x;
  if (idx >= 16 * 255 * 255) return;
  int xo = idx % 255; int tmp = idx / 255; int yo = tmp % 255; int b = tmp / 255;
  float acc[4][16];
#pragma unroll
  for (int p = 0; p < 4; p++)
#pragma unroll
  for (int c = 0; c < 16; c++) acc[p][c] = bias[c];
#pragma unroll
  for (int ky = 0; ky < 3; ky++)
#pragma unroll
  for (int kx = 0; kx < 3; kx++) {
    float xv[4][3];
#pragma unroll
    for (int py = 0; py < 2; py++)
#pragma unroll
    for (int px = 0; px < 2; px++) {
      const float* xp = x + ((size_t)(b * 512 + yo * 2 + py + ky) * 512 + (xo * 2 + px + kx)) * 3;
      xv[py * 2 + px][0] = xp[0];
      xv[py * 2 + px][1] = xp[1];
      xv[py * 2 + px][2] = xp[2];
    }
#pragma unroll
    for (int ci = 0; ci < 3; ci++)
#pragma unroll
    for (int c = 0; c < 16; c++) {
      float wv = w[((ky * 3 + kx) * 3 + ci) * 16 + c];   // uniform -> s_load
#pragma unroll
      for (int p = 0; p < 4; p++) acc[p][c] = fmaf(xv[p][ci], wv, acc[p][c]);
    }
  }
  bf16* op = out + (size_t)idx * 16;
#pragma unroll
  for (int c = 0; c < 16; c++) {
    float v = fmaxf(fmaxf(acc[0][c], acc[1][c]), fmaxf(acc[2][c], acc[3][c]));
    op[c] = (bf16)fmaxf(v, 0.f);
  }
}

// ---------------------------------------------------------------------------
// conv2 + ReLU + maxpool + pad(1) + patch-extract. Input halo in LDS (36 KB),
// weights via uniform scalar loads, pool window unrolled (acc[4][16]).
// ---------------------------------------------------------------------------
__global__ __launch_bounds__(256) void conv2_pool_patch(const bf16* __restrict__ in,
    const float* __restrict__ w, const float* __restrict__ bias,
    bf16* __restrict__ patches) {
  __shared__ bf16 xs[34 * 34 * 16];   // 36.1 KB
  int t = threadIdx.x;
  int tx = blockIdx.x, ty = blockIdx.y, b = blockIdx.z;
  int r0 = 32 * ty - 2, c0 = 32 * tx - 2;
  for (int i = t; i < 1156; i += 256) {
    int rr = i / 34, cc = i % 34;
    int gr = min(max(r0 + rr, 0), 254), gc = min(max(c0 + cc, 0), 254);
    const bf16* ip = in + ((size_t)(b * 255 + gr) * 255 + gc) * 16;
    uint4 v0 = *(const uint4*)ip;
    uint4 v1 = *(const uint4*)(ip + 8);
    *(uint4*)&xs[i * 16] = v0;
    *(uint4*)&xs[i * 16 + 8] = v1;
  }
  __syncthreads();
  int py_ = t >> 4, px_ = t & 15;
  int yp = ty * 16 + py_, xp = tx * 16 + px_;
  bf16* op = patches + ((size_t)(b * 64 + ty * 8 + tx) * 4096 + py_ * 256 + px_ * 16);
  if (yp == 0 || yp == 127 || xp == 0 || xp == 127) {
#pragma unroll
    for (int c = 0; c < 16; c++) op[c] = (bf16)0.f;
    return;
  }
  float acc[4][16];
#pragma unroll
  for (int p = 0; p < 4; p++)
#pragma unroll
  for (int c = 0; c < 16; c++) acc[p][c] = bias[c];
  for (int ky = 0; ky < 3; ky++)
  for (int kx = 0; kx < 3; kx++) {
    int base = ky * 3 + kx;
#pragma unroll
    for (int ch = 0; ch < 2; ch++) {
      float vv[4][8];
#pragma unroll
      for (int py = 0; py < 2; py++)
#pragma unroll
      for (int px = 0; px < 2; px++) {
        uint4 rw = *(const uint4*)&xs[((2 * py_ + py + ky) * 34 + (2 * px_ + px + kx)) * 16 + ch * 8];
        float* vp = vv[py * 2 + px];
        vp[0] = bflo(rw.x); vp[1] = bfhi(rw.x); vp[2] = bflo(rw.y); vp[3] = bfhi(rw.y);
        vp[4] = bflo(rw.z); vp[5] = bfhi(rw.z); vp[6] = bflo(rw.w); vp[7] = bfhi(rw.w);
      }
#pragma unroll
      for (int ci = 0; ci < 8; ci++)
#pragma unroll
      for (int c = 0; c < 16; c++) {
        float wv = w[(base * 16 + ch * 8 + ci) * 16 + c];   // uniform -> s_load
#pragma unroll
        for (int p = 0; p < 4; p++) acc[p][c] = fmaf(vv[p][ci], wv, acc[p][c]);
      }
    }
  }
#pragma unroll
  for (int c = 0; c < 16; c++) {
    float v = fmaxf(fmaxf(acc[0][c], acc[1][c]), fmaxf(acc[2][c], acc[3][c]));
    op[c] = (bf16)fmaxf(v, 0.f);
  }
}

// ---------------------------------------------------------------------------
// 64x64-tile bf16 MFMA GEMM, double-buffered LDS, ONE barrier per K-iter:
// DMA for tile k+1 is issued right after the barrier, so its latency is
// hidden behind tile k's MFMA work before the next barrier's vmcnt drain.
// MODE 0: fp32 partial (blockIdx.z = split slice). MODE 1: bias+relu -> bf16.
// ---------------------------------------------------------------------------
template<int MODE>
__global__ __launch_bounds__(256) void gemm64(const bf16* __restrict__ A,
    const bf16* __restrict__ Bt, const float* __restrict__ bias,
    float* __restrict__ Cf, bf16* __restrict__ Cb, int N, int K, int KC) {
  __shared__ bf16 As[2][4096];
  __shared__ bf16 Bs[2][4096];
  int s = blockIdx.z;
  int bm = blockIdx.y * 64, bn = blockIdx.x * 64;
  int t = threadIdx.x, lane = t & 63, wave = t >> 6;
  int wm = (wave >> 1) * 32, wn = (wave & 1) * 32;
  int lq = lane >> 4, lr = lane & 15;
  f32x4 acc[2][2];
#pragma unroll
  for (int i = 0; i < 2; i++)
#pragma unroll
  for (int j = 0; j < 2; j++) acc[i][j] = (f32x4){0.f, 0.f, 0.f, 0.f};

  // staging: instr covers rows [wave*8, +8) and +32; lane -> row lane>>3, chunk lane&7
  int srow = wave * 8 + (lane >> 3);
  int sch = lane & 7;
  const bf16* Ag = A + (size_t)(bm + srow) * K + s * KC + sch * 8;
  const bf16* Bg = Bt + (size_t)(bn + srow) * K + s * KC + sch * 8;
  int so = wave * 512;

  gl_lds16(Ag, &As[0][so]); gl_lds16(Ag + 32 * (size_t)K, &As[0][so + 2048]);
  gl_lds16(Bg, &Bs[0][so]); gl_lds16(Bg + 32 * (size_t)K, &Bs[0][so + 2048]);

  int cur = 0;
  for (int kk = 0; kk < KC; kk += 64) {
    Ag += 64; Bg += 64;
    __syncthreads();   // drains vmcnt: buffer `cur` DMA (issued one iter ago) complete
    if (kk + 64 < KC) {
      int nxt = cur ^ 1;
      gl_lds16(Ag, &As[nxt][so]); gl_lds16(Ag + 32 * (size_t)K, &As[nxt][so + 2048]);
      gl_lds16(Bg, &Bs[nxt][so]); gl_lds16(Bg + 32 * (size_t)K, &Bs[nxt][so + 2048]);
    }
#pragma unroll
    for (int ks = 0; ks < 2; ks++) {
      int ao = ks * 32 + lq * 8;
      bf16x8 af0 = *(const bf16x8*)&As[cur][(wm + lr) * 64 + ao];
      bf16x8 af1 = *(const bf16x8*)&As[cur][(wm + 16 + lr) * 64 + ao];
      bf16x8 bf0 = *(const bf16x8*)&Bs[cur][(wn + lr) * 64 + ao];
      bf16x8 bf1 = *(const bf16x8*)&Bs[cur][(wn + 16 + lr) * 64 + ao];
      acc[0][0] = __builtin_amdgcn_mfma_f32_16x16x32_bf16(af0, bf0, acc[0][0], 0, 0, 0);
      acc[0][1] = __builtin_amdgcn_mfma_f32_16x16x32_bf16(af0, bf1, acc[0][1], 0, 0, 0);
      acc[1][0] = __builtin_amdgcn_mfma_f32_16x16x32_bf16(af1, bf0, acc[1][0], 0, 0, 0);
      acc[1][1] = __builtin_amdgcn_mfma_f32_16x16x32_bf16(af1, bf1, acc[1][1], 0, 0, 0);
    }
    cur ^= 1;
  }

  if (MODE == 0) {
    float* Cp = Cf + (size_t)s * 1024 * N;
#pragma unroll
    for (int i = 0; i < 2; i++)
#pragma unroll
    for (int j = 0; j < 2; j++) {
      int col = bn + wn + j * 16 + lr;
      int row0 = bm + wm + i * 16 + lq * 4;      // m89-verified C/D layout
#pragma unroll
      for (int r = 0; r < 4; r++)
        Cp[(size_t)(row0 + r) * N + col] = acc[i][j][r];
    }
  } else {
#pragma unroll
    for (int i = 0; i < 2; i++)
#pragma unroll
    for (int j = 0; j < 2; j++) {
      int col = bn + wn + j * 16 + lr;
      float bb = bias[col];
      int row0 = bm + wm + i * 16 + lq * 4;
#pragma unroll
      for (int r = 0; r < 4; r++) {
        float v = fmaxf(acc[i][j][r] + bb, 0.f);
        Cb[(size_t)(row0 + r) * N + col] = (bf16)v;
      }
    }
  }
}

// ---------------------------------------------------------------------------
// attention: one block per (b,h). QKV = fused split-K partials (2,1024,2304):
// cols [0,768)=q, [768,1536)=k, [1536,2304)=v. Bias added here.
// Output (B,H,S,D)-flat bf16 (reference reshape quirk).
// ---------------------------------------------------------------------------
#define QKVN 2304
#define QKVP 2359296
__global__ __launch_bounds__(256) void attn_kernel(const float* __restrict__ QKV,
    const float* __restrict__ bq, const float* __restrict__ bk, const float* __restrict__ bv,
    bf16* __restrict__ Aout) {
  __shared__ alignas(16) float qs[64 * 68];   // later reused as V^T [d][s]
  __shared__ alignas(16) float ks[64 * 68];
  __shared__ alignas(16) float ss[64 * 68];
  int t = threadIdx.x;
  int bh = blockIdx.x; int b = bh / 12, h = bh % 12;
  size_t rb = (size_t)(b * 64) * QKVN;
  const float* q0 = QKV + rb + h * 64;
  const float* k0 = QKV + rb + 768 + h * 64;
  const float* v0 = QKV + rb + 1536 + h * 64;
  {
    int s = t >> 2, qd = (t & 3) * 16;
#pragma unroll
    for (int j = 0; j < 16; j += 4) {
      float4 qa = *(const float4*)(q0 + (size_t)s * QKVN + qd + j);
      float4 qb2 = *(const float4*)(q0 + QKVP + (size_t)s * QKVN + qd + j);
      float4 qb4 = *(const float4*)(bq + h * 64 + qd + j);
      float4 ka = *(const float4*)(k0 + (size_t)s * QKVN + qd + j);
      float4 kb2 = *(const float4*)(k0 + QKVP + (size_t)s * QKVN + qd + j);
      float4 kb4 = *(const float4*)(bk + h * 64 + qd + j);
      qs[s * 68 + qd + j + 0] = qa.x + qb2.x + qb4.x;
      qs[s * 68 + qd + j + 1] = qa.y + qb2.y + qb4.y;
      qs[s * 68 + qd + j + 2] = qa.z + qb2.z + qb4.z;
      qs[s * 68 + qd + j + 3] = qa.w + qb2.w + qb4.w;
      ks[s * 68 + qd + j + 0] = ka.x + kb2.x + kb4.x;
      ks[s * 68 + qd + j + 1] = ka.y + kb2.y + kb4.y;
      ks[s * 68 + qd + j + 2] = ka.z + kb2.z + kb4.z;
      ks[s * 68 + qd + j + 3] = ka.w + kb2.w + kb4.w;
    }
  }
  __syncthreads();
  int r = t >> 4, c = t & 15;
  {
    float sc[4][4];
#pragma unroll
    for (int i = 0; i < 4; i++)
#pragma unroll
    for (int j = 0; j < 4; j++) sc[i][j] = 0.f;
    for (int k = 0; k < 64; k += 4) {
      float4 qv[4], kv[4];
#pragma unroll
      for (int i = 0; i < 4; i++) qv[i] = *(const float4*)&qs[(r + 16 * i) * 68 + k];
#pragma unroll
      for (int j = 0; j < 4; j++) kv[j] = *(const float4*)&ks[(c + 16 * j) * 68 + k];
#pragma unroll
      for (int i = 0; i < 4; i++)
#pragma unroll
      for (int j = 0; j < 4; j++)
        sc[i][j] += qv[i].x * kv[j].x + qv[i].y * kv[j].y + qv[i].z * kv[j].z + qv[i].w * kv[j].w;
    }
#pragma unroll
    for (int i = 0; i < 4; i++)
#pragma unroll
    for (int j = 0; j < 4; j++)
      ss[(r + 16 * i) * 68 + c + 16 * j] = sc[i][j] * 0.125f;
  }
  __syncthreads();
  {  // V^T into qs with partial-sum + bias
    int d = t & 63, s0 = (t >> 6) * 16;
    float bvd = bv[h * 64 + d];
    alignas(16) float vv[16];
#pragma unroll
    for (int i = 0; i < 16; i++)
      vv[i] = v0[(size_t)(s0 + i) * QKVN + d] + v0[QKVP + (size_t)(s0 + i) * QKVN + d] + bvd;
#pragma unroll
    for (int i = 0; i < 16; i += 4) *(float4*)&qs[d * 68 + s0 + i] = *(float4*)&vv[i];
  }
  {  // softmax
    int lane = t & 63, wave = t >> 6;
    for (int rr = 0; rr < 16; rr++) {
      int row = wave * 16 + rr;
      float v = ss[row * 68 + lane];
      float m = v;
#pragma unroll
      for (int off = 32; off > 0; off >>= 1) m = fmaxf(m, __shfl_xor(m, off));
      float e = __expf(v - m);
      float ssum = e;
#pragma unroll
      for (int off = 32; off > 0; off >>= 1) ssum += __shfl_xor(ssum, off);
      ss[row * 68 + lane] = e / ssum;
    }
  }
  __syncthreads();
  {
    float oc[4][4];
#pragma unroll
    for (int i = 0; i < 4; i++)
#pragma unroll
    for (int j = 0; j < 4; j++) oc[i][j] = 0.f;
    for (int k = 0; k < 64; k += 4) {
      float4 pv[4], vv[4];
#pragma unroll
      for (int i = 0; i < 4; i++) pv[i] = *(const float4*)&ss[(r + 16 * i) * 68 + k];
#pragma unroll
      for (int j = 0; j < 4; j++) vv[j] = *(const float4*)&qs[(c + 16 * j) * 68 + k];
#pragma unroll
      for (int i = 0; i < 4; i++)
#pragma unroll
      for (int j = 0; j < 4; j++)
        oc[i][j] += pv[i].x * vv[j].x + pv[i].y * vv[j].y + pv[i].z * vv[j].z + pv[i].w * vv[j].w;
    }
    bf16* ob = Aout + (size_t)b * 49152 + h * 4096;
#pragma unroll
    for (int i = 0; i < 4; i++)
#pragma unroll
    for (int j = 0; j < 4; j++)
      ob[(r + 16 * i) * 64 + c + 16 * j] = (bf16)oc[i][j];
  }
}

// ---------------------------------------------------------------------------
// residual + S-way split-K partial sum + col bias + LayerNorm; fp32 + bf16 out
// ---------------------------------------------------------------------------
template<int S>
__global__ __launch_bounds__(256) void ln_kernel(const float* __restrict__ X,
    const float* __restrict__ Y, const float* __restrict__ yb,
    const float* __restrict__ g, const float* __restrict__ bta,
    float* __restrict__ Of, bf16* __restrict__ Ob) {
  int row = blockIdx.x, t = threadIdx.x;
  const float* xp = X + (size_t)row * 768;
  float vals[3]; float s = 0.f, s2 = 0.f;
#pragma unroll
  for (int i = 0; i < 3; i++) {
    int e = t + 256 * i;
    float v = xp[e] + yb[e];
#pragma unroll
    for (int p = 0; p < S; p++) v += Y[(size_t)p * 786432 + (size_t)row * 768 + e];
    vals[i] = v; s += v; s2 = fmaf(v, v, s2);
  }
#pragma unroll
  for (int off = 32; off > 0; off >>= 1) { s += __shfl_xor(s, off); s2 += __shfl_xor(s2, off); }
  __shared__ float rs[4], rs2[4];
  if ((t & 63) == 0) { rs[t >> 6] = s; rs2[t >> 6] = s2; }
  __syncthreads();
  s = rs[0] + rs[1] + rs[2] + rs[3];
  s2 = rs2[0] + rs2[1] + rs2[2] + rs2[3];
  float mean = s * (1.f / 768.f);
  float var = s2 * (1.f / 768.f) - mean * mean;
  float rstd = rsqrtf(var + 1e-6f);
  float* ofp = Of + (size_t)row * 768;
  bf16* obp = Ob + (size_t)row * 768;
#pragma unroll
  for (int i = 0; i < 3; i++) {
    int e = t + 256 * i;
    float o = (vals[i] - mean) * rstd * g[e] + bta[e];
    ofp[e] = o; obp[e] = (bf16)o;
  }
}

// S-partial reduce + bias -> fp32 + bf16
template<int S>
__global__ __launch_bounds__(256) void reduceN(const float* __restrict__ P,
    const float* __restrict__ bias, float* __restrict__ Of, bf16* __restrict__ Ob) {
  int row = blockIdx.x, t = threadIdx.x;
#pragma unroll
  for (int i = 0; i < 3; i++) {
    int e = t + 256 * i;
    float v = bias[e];
#pragma unroll
    for (int p = 0; p < S; p++) v += P[(size_t)p * 786432 + (size_t)row * 768 + e];
    Of[(size_t)row * 768 + e] = v;
    Ob[(size_t)row * 768 + e] = (bf16)v;
  }
}

// ---------------------------------------------------------------------------
// mean-pool + head + sigmoid
// ---------------------------------------------------------------------------
__global__ __launch_bounds__(256) void head_kernel(const float* __restrict__ T,
    const float* __restrict__ hw, const float* __restrict__ hbp, float* __restrict__ out) {
  int b = blockIdx.x, t = threadIdx.x;
  float acc = 0.f;
#pragma unroll
  for (int i = 0; i < 3; i++) {
    int e = t + 256 * i;
    float s = 0.f;
    for (int si = 0; si < 64; si++) s += T[(size_t)(b * 64 + si) * 768 + e];
    acc = fmaf(s * (1.f / 64.f), hw[e], acc);
  }
#pragma unroll
  for (int off = 32; off > 0; off >>= 1) acc += __shfl_xor(acc, off);
  __shared__ float rs[4];
  if ((t & 63) == 0) rs[t >> 6] = acc;
  __syncthreads();
  if (t == 0) {
    float z = rs[0] + rs[1] + rs[2] + rs[3] + hbp[0];
    out[b] = 1.f / (1.f + expf(-z));
  }
}

// ---------------------------------------------------------------------------
extern "C" void kernel_launch(void* const* d_in, const int* in_sizes, int n_in,
                              void* d_out, int out_size, void* d_ws, size_t ws_size,
                              hipStream_t stream) {
  const float* x     = (const float*)d_in[0];
  const float* c1w   = (const float*)d_in[1];
  const float* c1b   = (const float*)d_in[2];
  const float* c2w   = (const float*)d_in[3];
  const float* c2b   = (const float*)d_in[4];
  const float* projw = (const float*)d_in[5];
  const float* projb = (const float*)d_in[6];
  const float* Wq    = (const float*)d_in[7];
  const float* bq    = (const float*)d_in[8];
  const float* Wk    = (const float*)d_in[9];
  const float* bk    = (const float*)d_in[10];
  const float* Wv    = (const float*)d_in[11];
  const float* bv    = (const float*)d_in[12];
  const float* Wo    = (const float*)d_in[13];
  const float* bo    = (const float*)d_in[14];
  const float* W1    = (const float*)d_in[15];
  const float* b1    = (const float*)d_in[16];
  const float* W2    = (const float*)d_in[17];
  const float* b2    = (const float*)d_in[18];
  const float* ln1g  = (const float*)d_in[19];
  const float* ln1b  = (const float*)d_in[20];
  const float* ln2g  = (const float*)d_in[21];
  const float* ln2b  = (const float*)d_in[22];
  const float* headw = (const float*)d_in[23];
  const float* headb = (const float*)d_in[24];
  float* out = (float*)d_out;

  char* wp = (char*)d_ws;
  auto alloc = [&](size_t bytes) { char* p = wp; wp += (bytes + 255) & ~(size_t)255; return p; };
  bf16* c1p     = (bf16*)alloc((size_t)16 * 255 * 255 * 16 * 2);   // 33.3 MB
  bf16* patches = (bf16*)alloc((size_t)1024 * 4096 * 2);
  bf16* projT   = (bf16*)alloc((size_t)4096 * 768 * 2);
  bf16* WqkvT   = (bf16*)alloc((size_t)8 * 2304 * 768 * 2);        // fused q|k|v
  bf16* WoT     = (bf16*)alloc((size_t)8 * 768 * 768 * 2);
  bf16* W1T     = (bf16*)alloc((size_t)8 * 768 * 3072 * 2);
  bf16* W2T     = (bf16*)alloc((size_t)8 * 3072 * 768 * 2);
  float* pbuf   = (float*)alloc((size_t)2 * 1024 * 2304 * 4);      // shared split-K partials
  float* tf     = (float*)alloc((size_t)1024 * 768 * 4);
  bf16*  tb     = (bf16*)alloc((size_t)1024 * 768 * 2);
  bf16*  ab     = (bf16*)alloc((size_t)1024 * 768 * 2);
  float* o1f    = (float*)alloc((size_t)1024 * 768 * 4);
  bf16*  o1b    = (bf16*)alloc((size_t)1024 * 768 * 2);
  bf16*  hbuf   = (bf16*)alloc((size_t)1024 * 3072 * 2);

  // weight prep (re-done every call: harness re-poisons ws)
  wtrans<<<dim3(24, 128, 1), 256, 0, stream>>>(projw, projT, 4096, 768, 0, 0);
  wtrans<<<dim3(24, 24, 8), 256, 0, stream>>>(Wq, WqkvT,           768, 768, 589824, 1769472);
  wtrans<<<dim3(24, 24, 8), 256, 0, stream>>>(Wk, WqkvT + 589824,  768, 768, 589824, 1769472);
  wtrans<<<dim3(24, 24, 8), 256, 0, stream>>>(Wv, WqkvT + 1179648, 768, 768, 589824, 1769472);
  wtrans<<<dim3(24, 24, 8), 256, 0, stream>>>(Wo, WoT, 768, 768, 589824, 589824);
  wtrans<<<dim3(96, 24, 8), 256, 0, stream>>>(W1, W1T, 768, 3072, 2359296, 2359296);
  wtrans<<<dim3(24, 96, 8), 256, 0, stream>>>(W2, W2T, 3072, 768, 2359296, 2359296);

  conv1_pool<<<4065, 256, 0, stream>>>(x, c1w, c1b, c1p);
  conv2_pool_patch<<<dim3(8, 8, 16), 256, 0, stream>>>(c1p, c2w, c2b, patches);
  gemm64<0><<<dim3(12, 16, 4), 256, 0, stream>>>(patches, projT, nullptr, pbuf, nullptr, 768, 4096, 1024);
  reduceN<4><<<1024, 256, 0, stream>>>(pbuf, projb, tf, tb);

  for (int i = 0; i < 8; i++) {
    gemm64<0><<<dim3(36, 16, 2), 256, 0, stream>>>(tb, WqkvT + (size_t)i * 1769472,
        nullptr, pbuf, nullptr, 2304, 768, 384);
    attn_kernel<<<192, 256, 0, stream>>>(pbuf, bq + i * 768, bk + i * 768, bv + i * 768, ab);
    gemm64<0><<<dim3(12, 16, 4), 256, 0, stream>>>(ab, WoT + (size_t)i * 589824,
        nullptr, pbuf, nullptr, 768, 768, 192);
    ln_kernel<4><<<1024, 256, 0, stream>>>(tf, pbuf, bo + i * 768,
        ln1g + i * 768, ln1b + i * 768, o1f, o1b);
    gemm64<1><<<dim3(48, 16, 1), 256, 0, stream>>>(o1b, W1T + (size_t)i * 2359296,
        b1 + i * 3072, nullptr, hbuf, 3072, 768, 768);
    gemm64<0><<<dim3(12, 16, 4), 256, 0, stream>>>(hbuf, W2T + (size_t)i * 2359296,
        nullptr, pbuf, nullptr, 768, 3072, 768);
    ln_kernel<4><<<1024, 256, 0, stream>>>(o1f, pbuf, b2 + i * 768,
        ln2g + i * 768, ln2b + i * 768, tf, tb);
  }
  head_kernel<<<16, 256, 0, stream>>>(tf, headw, headb, out);
}